// Round 1
// baseline (1023.765 us; speedup 1.0000x reference)
//
#include <hip/hip_runtime.h>

// Problem constants: B=1024 queries, M=262144 bank rows, D=512.
// min_dist[b] = sqrt(max(2 - 2*max_m dot(xhat_b, y_m), 1e-12))  (both unit vectors)

#define B_Q   1024
#define M_BANK 262144
#define DIM   512
#define CM    128          // bank rows resident in LDS per chunk
#define LDA   520          // padded LDS row stride (bf16 elems): 1040B -> 2-way-free bank pattern
#define CHUNKS_PER_WG 8    // 256 wgs * 8 chunks * 128 rows = 262144
#define NWG   256

typedef __attribute__((ext_vector_type(8))) short short8;
typedef __attribute__((ext_vector_type(4))) float f32x4;

__device__ inline unsigned short f2bf(float f) {
  union { float f; unsigned u; } x; x.f = f;
  unsigned r = x.u + 0x7FFFu + ((x.u >> 16) & 1u);   // round-to-nearest-even
  return (unsigned short)(r >> 16);
}

// ---------- Kernel 1: normalize queries, convert to bf16 (1 wave per row) ----------
__global__ void normq_kernel(const float* __restrict__ X, unsigned short* __restrict__ Qn) {
  const int b = blockIdx.x;
  const int lane = threadIdx.x;  // 64
  const float4* row = (const float4*)(X + (size_t)b * DIM);
  float4 v0 = row[lane];
  float4 v1 = row[lane + 64];
  float ss = v0.x*v0.x + v0.y*v0.y + v0.z*v0.z + v0.w*v0.w
           + v1.x*v1.x + v1.y*v1.y + v1.z*v1.z + v1.w*v1.w;
  #pragma unroll
  for (int o = 32; o >= 1; o >>= 1) ss += __shfl_xor(ss, o);
  const float inv = 1.0f / sqrtf(ss);
  unsigned short* dst = Qn + (size_t)b * DIM;
  ushort4 o0 = make_ushort4(f2bf(v0.x*inv), f2bf(v0.y*inv), f2bf(v0.z*inv), f2bf(v0.w*inv));
  ushort4 o1 = make_ushort4(f2bf(v1.x*inv), f2bf(v1.y*inv), f2bf(v1.z*inv), f2bf(v1.w*inv));
  ((ushort4*)dst)[lane]      = o0;
  ((ushort4*)dst)[lane + 64] = o1;
}

// ---------- Kernel 2: main GEMM + row-max ----------
// wg = 256 threads (4 waves). Wave w owns b-cols [w*32, w*32+32) of each 128-wide b-tile.
// A (bank chunk) LDS-resident bf16 [128][520-padded]; B-fragments straight from global Qn (L2-hot).
__global__ __launch_bounds__(256, 1)
void patch_main(const float* __restrict__ bank, const unsigned short* __restrict__ Qn,
                float* __restrict__ partial) {
  __shared__ unsigned short bankT[CM * LDA];   // 133120 B
  __shared__ float runMax[B_Q];                // 4096 B  (total 137216 <= 160 KiB)

  const int tid  = threadIdx.x;
  const int lane = tid & 63;
  const int wave = tid >> 6;
  const int quad = lane >> 4;
  const int l16  = lane & 15;

  for (int i = tid; i < B_Q; i += 256) runMax[i] = -2.0f;

  const size_t mBase = (size_t)blockIdx.x * (CM * CHUNKS_PER_WG);

  for (int c = 0; c < CHUNKS_PER_WG; ++c) {
    __syncthreads();  // prior chunk's A-frag reads done before overwrite (also covers init)

    // ---- stage bank chunk: 128x512 fp32 -> bf16 LDS (coalesced 1KB/wave/iter) ----
    const float4* src = (const float4*)(bank + (mBase + (size_t)c * CM) * DIM);
    #pragma unroll 8
    for (int p = 0; p < 64; ++p) {
      int f4 = p * 256 + tid;            // 0..16383
      float4 v = src[f4];
      int row = f4 >> 7;                 // /128  (f4*4/512)
      int col = (f4 & 127) << 2;
      ushort4 o = make_ushort4(f2bf(v.x), f2bf(v.y), f2bf(v.z), f2bf(v.w));
      *(ushort4*)(bankT + row * LDA + col) = o;
    }
    __syncthreads();

    // ---- 8 b-tiles of 128 queries, full K accumulate, then max-reduce ----
    for (int bt = 0; bt < 8; ++bt) {
      f32x4 acc[8][2];
      #pragma unroll
      for (int i = 0; i < 8; ++i) {
        f32x4 z = {0.f, 0.f, 0.f, 0.f};
        acc[i][0] = z; acc[i][1] = z;
      }
      const unsigned short* qbase = Qn + (size_t)(bt * 128 + wave * 32 + l16) * DIM + quad * 8;
      const unsigned short* abase = bankT + l16 * LDA + quad * 8;

      #pragma unroll 4
      for (int ks = 0; ks < 16; ++ks) {   // k-step = 32
        const int k0 = ks * 32;
        short8 b0 = *(const short8*)(qbase + k0);             // B-frag, col = ..+l16
        short8 b1 = *(const short8*)(qbase + 16 * DIM + k0);  // col +16
        short8 a[8];
        #pragma unroll
        for (int i = 0; i < 8; ++i)
          a[i] = *(const short8*)(abase + i * 16 * LDA + k0); // A-frag row = i*16+l16
        #pragma unroll
        for (int i = 0; i < 8; ++i) {
          acc[i][0] = __builtin_amdgcn_mfma_f32_16x16x32_bf16(a[i], b0, acc[i][0], 0, 0, 0);
          acc[i][1] = __builtin_amdgcn_mfma_f32_16x16x32_bf16(a[i], b1, acc[i][1], 0, 0, 0);
        }
      }

      // C/D layout: col = lane&15 (query), row = quad*4 + reg (bank row). Max over all rows.
      #pragma unroll
      for (int j = 0; j < 2; ++j) {
        float mx = -2.0f;
        #pragma unroll
        for (int i = 0; i < 8; ++i) {
          f32x4 v = acc[i][j];
          mx = fmaxf(mx, fmaxf(fmaxf(v.x, v.y), fmaxf(v.z, v.w)));
        }
        mx = fmaxf(mx, __shfl_xor(mx, 16));
        mx = fmaxf(mx, __shfl_xor(mx, 32));
        if (lane < 16) {   // wave-exclusive b columns: no atomics needed
          int b = bt * 128 + wave * 32 + j * 16 + lane;
          runMax[b] = fmaxf(runMax[b], mx);
        }
      }
    }
  }

  __syncthreads();
  for (int i = tid; i < B_Q; i += 256)
    partial[(size_t)blockIdx.x * B_Q + i] = runMax[i];
}

// ---------- Kernel 3: reduce partials, convert to distance ----------
__global__ void finalize_kernel(const float* __restrict__ partial, float* __restrict__ out) {
  const int b = blockIdx.x;      // 1024
  const int lane = threadIdx.x;  // 64
  float m = -2.0f;
  #pragma unroll
  for (int r = 0; r < NWG / 64; ++r)
    m = fmaxf(m, partial[(size_t)(r * 64 + lane) * B_Q + b]);
  #pragma unroll
  for (int o = 32; o >= 1; o >>= 1) m = fmaxf(m, __shfl_xor(m, o));
  if (lane == 0) out[b] = sqrtf(fmaxf(2.0f - 2.0f * m, 1e-12f));
}

extern "C" void kernel_launch(void* const* d_in, const int* in_sizes, int n_in,
                              void* d_out, int out_size, void* d_ws, size_t ws_size,
                              hipStream_t stream) {
  const float* feats = (const float*)d_in[0];   // [1024, 512] fp32
  const float* bank  = (const float*)d_in[1];   // [262144, 512] fp32, pre-normalized
  float* out = (float*)d_out;                   // [1024] fp32

  unsigned short* Qn = (unsigned short*)d_ws;                      // 1 MB bf16 queries
  float* partial = (float*)((char*)d_ws + (size_t)B_Q * DIM * 2);  // 1 MB partial maxes

  normq_kernel<<<B_Q, 64, 0, stream>>>(feats, Qn);
  patch_main<<<NWG, 256, 0, stream>>>(bank, Qn, partial);
  finalize_kernel<<<B_Q, 64, 0, stream>>>(partial, out);
}